// Round 3
// baseline (3382.530 us; speedup 1.0000x reference)
//
#include <hip/hip_runtime.h>
#include <math.h>

#define EPSC   1e-6f
#define BNEPS  1e-5f
#define NSWEEP_BULK 6
#define NSWEEP_STAT 8

#define NMAT   16384                // B*C matrices

// static workspace layout (float offsets)
#define OFF_BM      0
#define OFF_BMSQ    4096
#define OFF_BMISQ   8192
#define OFF_MEANSQ  12288
#define OFF_RMISQ   16384
#define OFF_SVEC    20480
#define OFF_PART1   32768           // 256*4096 (k_mean1 only; overlaps gtblk in time)
#define OFF_DYN     32768           // dynamic region: gtblk[NBLK*4*1024] | sllblk[NBLK*128] | gt2[64*1024]

// ---------- device helpers ----------

// One-sided (Hestenes) Jacobi. Lane k of each 32-lane half-wave owns column k.
// XOR-mask pairing: masks 1..31 are perfect matchings covering all pairs/sweep.
template<int SWEEPS>
__device__ __forceinline__ void jacobi32(float a[32], int k) {
    float alpha = 0.f;
#pragma unroll
    for (int i = 0; i < 32; ++i) alpha = fmaf(a[i], a[i], alpha);
#pragma unroll 1
    for (int sweep = 0; sweep < SWEEPS; ++sweep) {
#pragma unroll 1
        for (int m = 1; m < 32; ++m) {
            float q[32];
#pragma unroll
            for (int i = 0; i < 32; ++i) q[i] = __shfl_xor(a[i], m);
            float beta = __shfl_xor(alpha, m);
            // dot(a,q): 8 independent 4-deep chains
            float g0 = 0.f, g1 = 0.f, g2 = 0.f, g3 = 0.f;
            float g4 = 0.f, g5 = 0.f, g6 = 0.f, g7 = 0.f;
#pragma unroll
            for (int i = 0; i < 32; i += 8) {
                g0 = fmaf(a[i+0], q[i+0], g0);
                g1 = fmaf(a[i+1], q[i+1], g1);
                g2 = fmaf(a[i+2], q[i+2], g2);
                g3 = fmaf(a[i+3], q[i+3], g3);
                g4 = fmaf(a[i+4], q[i+4], g4);
                g5 = fmaf(a[i+5], q[i+5], g5);
                g6 = fmaf(a[i+6], q[i+6], g6);
                g7 = fmaf(a[i+7], q[i+7], g7);
            }
            float gam = ((g0 + g1) + (g2 + g3)) + ((g4 + g5) + (g6 + g7));
            bool isp = (k < (k ^ m));
            float aa = isp ? alpha : beta;   // ||a_p||^2
            float bb = isp ? beta  : alpha;  // ||a_q||^2
            bool tiny = (fabsf(gam) < 1e-30f);
            float tau = (bb - aa) / (2.f * gam);
            float t = copysignf(1.f, tau) / (fabsf(tau) + sqrtf(fmaf(tau, tau, 1.f)));
            t = tiny ? 0.f : t;
            float c = rsqrtf(fmaf(t, t, 1.f));
            float s = t * c;
            float se = isp ? -s : s;
            float te = isp ? -t : t;
#pragma unroll
            for (int i = 0; i < 32; ++i) a[i] = fmaf(se, q[i], c * a[i]);
            alpha = fmaf(te, gam, alpha);    // alpha' = alpha -/+ t*gamma
        }
    }
}

// y = M v; M 32x32 (LDS or global), columns of 32 floats; broadcast reads.
__device__ __forceinline__ void matvec32(const float* M, const float v[32], float y[32]) {
#pragma unroll
    for (int i = 0; i < 32; ++i) y[i] = 0.f;
#pragma unroll
    for (int j = 0; j < 32; ++j) {
        const float4* col = (const float4*)(M + j * 32);
        float vj = v[j];
#pragma unroll
        for (int cc = 0; cc < 8; ++cc) {
            float4 r = col[cc];
            y[cc*4+0] = fmaf(vj, r.x, y[cc*4+0]);
            y[cc*4+1] = fmaf(vj, r.y, y[cc*4+1]);
            y[cc*4+2] = fmaf(vj, r.z, y[cc*4+2]);
            y[cc*4+3] = fmaf(vj, r.w, y[cc*4+3]);
        }
    }
}

__device__ __forceinline__ void read_vec(const float* M, int k, float v[32]) {
    const float4* src = (const float4*)(M + k * 32);
#pragma unroll
    for (int cc = 0; cc < 8; ++cc) {
        float4 r = src[cc];
        v[cc*4+0] = r.x; v[cc*4+1] = r.y; v[cc*4+2] = r.z; v[cc*4+3] = r.w;
    }
}

__device__ __forceinline__ void stage_vec(float* M, int k, const float v[32]) {
    float4* dst = (float4*)(M + k * 32);
#pragma unroll
    for (int cc = 0; cc < 8; ++cc)
        dst[cc] = make_float4(v[cc*4+0], v[cc*4+1], v[cc*4+2], v[cc*4+3]);
}

// out[i] (+)= sum_j (coef_j * A[k][j]) * Acol_j[i]   (A column-major in LDS)
template<bool ACC, bool USE_COEF>
__device__ __forceinline__ void recon32(const float* Acols, const float* coef, int k, float out[32]) {
    if (!ACC) {
#pragma unroll
        for (int i = 0; i < 32; ++i) out[i] = 0.f;
    }
    for (int j = 0; j < 32; ++j) {
        float w = Acols[j * 32 + k];          // bank k per lane: conflict-free
        if (USE_COEF) w *= coef[j];
        const float4* col = (const float4*)(Acols + j * 32);
#pragma unroll
        for (int cc = 0; cc < 8; ++cc) {
            float4 r = col[cc];
            out[cc*4+0] = fmaf(w, r.x, out[cc*4+0]);
            out[cc*4+1] = fmaf(w, r.y, out[cc*4+1]);
            out[cc*4+2] = fmaf(w, r.z, out[cc*4+2]);
            out[cc*4+3] = fmaf(w, r.w, out[cc*4+3]);
        }
    }
}

// ---------- kernels ----------

__global__ __launch_bounds__(256) void k_mean1(const float* __restrict__ X, float* __restrict__ part) {
    int bi = blockIdx.x;
    int tid = threadIdx.x;
    const float* xb = X + (size_t)bi * 16 * 4096;
#pragma unroll
    for (int q = 0; q < 16; ++q) {
        int e = q * 256 + tid;
        float acc = 0.f;
        for (int b = 0; b < 16; ++b) acc += xb[(size_t)b * 4096 + e];
        part[(size_t)bi * 4096 + e] = acc;
    }
}

__global__ __launch_bounds__(256) void k_mean2(const float* __restrict__ part, float* __restrict__ bm) {
    int e = blockIdx.x * 256 + threadIdx.x;   // 16 blocks
    float acc = 0.f;
    for (int bi = 0; bi < 256; ++bi) acc += part[(size_t)bi * 4096 + e];
    bm[e] = acc * (1.f / 4096.f);
}

// eig(bm[c]) -> bm_sq, bm_isq ; eig(mean[c]) -> mean_sq.  1 block, 8 half-waves.
__global__ __launch_bounds__(256) void k_prep(const float* __restrict__ wsbm, const float* __restrict__ meang,
                                              float* __restrict__ bmsq, float* __restrict__ bmisq,
                                              float* __restrict__ msq) {
    __shared__ __align__(16) float mat[8][1024];
    __shared__ __align__(16) float aslot[8][1024];
    __shared__ float coefA[8][32];
    __shared__ float coefB[4][32];
    int tid = threadIdx.x;
    for (int i = tid; i < 4096; i += 256) {
        ((float*)mat)[i] = wsbm[i];
        ((float*)mat)[4096 + i] = meang[i];
    }
    __syncthreads();
    int hwl = tid >> 5, k = tid & 31;
    float a[32];
    read_vec(mat[hwl], k, a);
    jacobi32<NSWEEP_STAT>(a, k);
    float al = 0.f;
#pragma unroll
    for (int i = 0; i < 32; ++i) al = fmaf(a[i], a[i], al);
    al = fmaxf(al, 1e-30f);
    float lam = sqrtf(al);
    float inv_al = 1.f / al;
    if (hwl < 4) {
        float wc = fmaxf(lam, EPSC);
        float sqw = sqrtf(wc);
        coefA[hwl][k] = sqw * inv_al;            // sqrtm coef
        coefB[hwl][k] = (1.f / sqw) * inv_al;    // invsqrtm coef
    } else {
        float wc = fmaxf(lam, 0.f);
        coefA[hwl][k] = sqrtf(wc) * inv_al;      // sqrtm(mean) coef
    }
    stage_vec(aslot[hwl], k, a);
    __syncthreads();
    float o[32];
    recon32<false, true>(aslot[hwl], coefA[hwl], k, o);
    if (hwl < 4) {
        float* dst = bmsq + hwl * 1024 + k * 32;
#pragma unroll
        for (int i = 0; i < 32; ++i) dst[i] = o[i];
        recon32<false, true>(aslot[hwl], coefB[hwl], k, o);
        float* dst2 = bmisq + hwl * 1024 + k * 32;
#pragma unroll
        for (int i = 0; i < 32; ++i) dst2[i] = o[i];
    } else {
        float* dst = msq + (hwl - 4) * 1024 + k * 32;
#pragma unroll
        for (int i = 0; i < 32; ++i) dst[i] = o[i];
    }
}

// pass A: S = bm_isq X bm_isq, eig, GT partial += logm(S), sll += sum log^2(lam).
// bm_isq read from global (L1-resident broadcast). gt accumulates via global RMW
// so nothing fat stays live across jacobi (spill avoidance, see round-2 post-mortem).
__global__ __launch_bounds__(256) void k_passA(const float* __restrict__ X, const float* __restrict__ bmisq_g,
                                               float* __restrict__ gtblk, float* __restrict__ sllblk,
                                               int rounds, int nhw) {
    __shared__ __align__(16) float slot[8][1024];
    __shared__ float coef[8][32];
    __shared__ float sllred[8][32];
    int tid = threadIdx.x;
    int hwl = tid >> 5, k = tid & 31;
    int hw = blockIdx.x * 8 + hwl;
    int c = hwl & 3;                    // == hw & 3 (nhw multiple of 4)
    const float* bmc = bmisq_g + c * 1024;
    float sll = 0.f;
#pragma unroll 1
    for (int r = 0; r < rounds; ++r) {
        int g = hw + r * nhw;
        const float4* xg = (const float4*)(X + (size_t)g * 1024);
        float4* xs = (float4*)slot[hwl];
#pragma unroll
        for (int i = 0; i < 8; ++i) xs[i * 32 + k] = xg[i * 32 + k];
        __syncthreads();
        float a[32];
        {
            float mk[32]; read_vec(bmc, k, mk);        // col k of bm_isq (symmetric)
            float y[32];  matvec32(slot[hwl], mk, y);  // X * mk
            matvec32(bmc, y, a);                       // col k of S
        }
        jacobi32<NSWEEP_BULK>(a, k);
        float al = 0.f;
#pragma unroll
        for (int i = 0; i < 32; ++i) al = fmaf(a[i], a[i], al);
        al = fmaxf(al, 1e-30f);
        float lam = sqrtf(al);
        float l = logf(fmaxf(lam, EPSC));
        sll = fmaf(l, l, sll);
        __syncthreads();
        stage_vec(slot[hwl], k, a);
        coef[hwl][k] = l / al;                     // log(lam)/lam^2
        __syncthreads();
        float gt[32];
        recon32<false, true>(slot[hwl], coef[hwl], k, gt);  // logm(S) col k
        __syncthreads();
        if (hwl >= 4) stage_vec(slot[hwl], k, gt);
        __syncthreads();
        if (hwl < 4) {
            const float* p = slot[hwl + 4] + k * 32;
            float* dst = gtblk + ((size_t)blockIdx.x * 4 + c) * 1024 + k * 32;
            if (r == 0) {
#pragma unroll
                for (int i = 0; i < 32; ++i) dst[i] = gt[i] + p[i];
            } else {
#pragma unroll
                for (int i = 0; i < 32; ++i) dst[i] += gt[i] + p[i];
            }
        }
        __syncthreads();
    }
    sllred[hwl][k] = sll;
    __syncthreads();
    if (hwl < 4)
        sllblk[((size_t)blockIdx.x * 4 + c) * 32 + k] = sll + sllred[hwl + 4][k];
}

// reduce NBLK block-partials -> 16 segment partials per channel (T = NBLK/16)
__global__ __launch_bounds__(256) void k_red(const float* __restrict__ gtblk, float* __restrict__ gt2, int T) {
    int bi = blockIdx.x;                // 64
    int c = bi & 3, seg = bi >> 2;
    int tid = threadIdx.x;
#pragma unroll
    for (int q = 0; q < 4; ++q) {
        int e = q * 256 + tid;
        float acc = 0.f;
        for (int t = 0; t < T; ++t) {
            int blk = seg * T + t;
            acc += gtblk[((size_t)blk * 4 + c) * 1024 + e];
        }
        gt2[((size_t)seg * 4 + c) * 1024 + e] = acc;
    }
}

// finish GT, batch_var, s; eig(GT) -> expm -> rm; eig(rm) -> rm_isq.
__global__ __launch_bounds__(256) void k_stats(const float* __restrict__ gt2, const float* __restrict__ sllblk,
                                               const float* __restrict__ stdg, const float* __restrict__ bmsq_g,
                                               float* __restrict__ rmisq_g, float* __restrict__ svec_g,
                                               int slltot) {
    __shared__ __align__(16) float GTl[4][1024];
    __shared__ __align__(16) float bmsq[4][1024];
    __shared__ __align__(16) float slot[8][1024];
    __shared__ float coef[4][32];
    __shared__ float sred[256];
    int tid = threadIdx.x;
    for (int i = tid; i < 4096; i += 256) {
        int cc = i >> 10, e = i & 1023;
        float acc = 0.f;
        for (int seg = 0; seg < 16; ++seg) acc += gt2[((size_t)seg * 4 + cc) * 1024 + e];
        ((float*)GTl)[i] = acc * (1.f / 4096.f);
        ((float*)bmsq)[i] = bmsq_g[i];
    }
    float sacc = 0.f;
    for (int idx = tid; idx < slltot; idx += 256) sacc += sllblk[idx];  // channel ((tid>>5)&3) fixed
    sred[tid] = sacc;
    __syncthreads();
    if (tid < 4) {
        float tot = 0.f;
        for (int kk = 0; kk < 32; ++kk) tot += sred[tid * 32 + kk] + sred[tid * 32 + 128 + kk];
        float sll_mean = tot * (1.f / 4096.f);
        float ssq = 0.f;
        for (int e = 0; e < 1024; ++e) { float v = GTl[tid][e]; ssq = fmaf(v, v, ssq); }
        float bvar = fmaxf(sll_mean - ssq, 0.f);     // batch_var = E||XT||^2 - ||GT||^2
        float s = stdg[tid] / sqrtf(bvar + BNEPS);
        svec_g[tid] = s;
    }
    __syncthreads();
    int hwl = tid >> 5, k = tid & 31;
    // stage 1: eig(GT) (indefinite -> Rayleigh sign), expm, rm = bm_sq expm(GT) bm_sq
    if (hwl < 4) {
        int c = hwl;
        float a[32]; read_vec(GTl[c], k, a);
        jacobi32<NSWEEP_STAT>(a, k);
        float s2 = 0.f;
#pragma unroll
        for (int i = 0; i < 32; ++i) s2 = fmaf(a[i], a[i], s2);
        s2 = fmaxf(s2, 1e-30f);
        float y[32]; matvec32(GTl[c], a, y);
        float num = 0.f;
#pragma unroll
        for (int i = 0; i < 32; ++i) num = fmaf(a[i], y[i], num);
        float rho = num / s2;                       // signed eigenvalue
        coef[hwl][k] = expf(rho) / s2;
        stage_vec(slot[hwl], k, a);
    }
    __syncthreads();
    if (hwl < 4) {
        float ex[32];
        recon32<false, true>(slot[hwl], coef[hwl], k, ex);   // expm(GT) col k
        stage_vec(slot[hwl + 4], k, ex);
    }
    __syncthreads();
    if (hwl < 4) {
        int c = hwl;
        float v1[32]; read_vec(bmsq[c], k, v1);
        float v2[32]; matvec32(slot[hwl + 4], v1, v2);
        float rmc[32]; matvec32(bmsq[c], v2, rmc);           // rm col k
        stage_vec(slot[hwl], k, rmc);
    }
    __syncthreads();
    // stage 2: eig(rm) -> rm_isq
    if (hwl < 4) {
        float a[32]; read_vec(slot[hwl], k, a);
        jacobi32<NSWEEP_STAT>(a, k);
        float al = 0.f;
#pragma unroll
        for (int i = 0; i < 32; ++i) al = fmaf(a[i], a[i], al);
        al = fmaxf(al, 1e-30f);
        float lam = sqrtf(al);
        float wc = fmaxf(lam, EPSC);
        coef[hwl][k] = (1.f / sqrtf(wc)) / al;
        stage_vec(slot[hwl], k, a);
    }
    __syncthreads();
    if (hwl < 4) {
        float o[32];
        recon32<false, true>(slot[hwl], coef[hwl], k, o);
        float* dst = rmisq_g + hwl * 1024 + k * 32;
#pragma unroll
        for (int i = 0; i < 32; ++i) dst[i] = o[i];
    }
}

// pass B: inner = rm_isq X rm_isq, eig, Xn = C C^T with C = mean_sq (A' diag(sqrt(lam^s)/lam)).
// rm_isq / mean_sq / svec read from global (broadcast); LDS = exactly 32KB.
__global__ __launch_bounds__(256) void k_passB(const float* __restrict__ X, const float* __restrict__ rmisq_g,
                                               const float* __restrict__ msq_g, const float* __restrict__ svec_g,
                                               float* __restrict__ out) {
    __shared__ __align__(16) float slot[8][1024];
    int tid = threadIdx.x;
    int hwl = tid >> 5, k = tid & 31;
    int hw = blockIdx.x * 8 + hwl;
    int c = hwl & 3;
    const float* rmc_g = rmisq_g + c * 1024;
    const float* msqc  = msq_g + c * 1024;
    float sv = svec_g[c];                           // uniform per half-wave, L1 hit
    {
        int g = hw;
        const float4* xg = (const float4*)(X + (size_t)g * 1024);
        float4* xs = (float4*)slot[hwl];
#pragma unroll
        for (int i = 0; i < 8; ++i) xs[i * 32 + k] = xg[i * 32 + k];
        __syncthreads();
        float a[32];
        {
            float t1[32]; read_vec(rmc_g, k, t1);
            float t2[32]; matvec32(slot[hwl], t1, t2);
            matvec32(rmc_g, t2, a);                  // inner col k
        }
        jacobi32<NSWEEP_BULK>(a, k);
        float al = 0.f;
#pragma unroll
        for (int i = 0; i < 32; ++i) al = fmaf(a[i], a[i], al);
        al = fmaxf(al, 1e-30f);
        float lam = sqrtf(al);
        float wc = fmaxf(lam, EPSC);
        float pw = expf(sv * logf(wc));              // lam^s
        float scl = sqrtf(pw / al);
#pragma unroll
        for (int i = 0; i < 32; ++i) a[i] *= scl;
        float cc[32]; matvec32(msqc, a, cc);         // C col k = mean_sq * bh
        __syncthreads();
        stage_vec(slot[hwl], k, cc);
        __syncthreads();
        float xn[32];
        recon32<false, false>(slot[hwl], (const float*)nullptr, k, xn);  // Xn = C C^T col k
        float* dst = out + (size_t)g * 1024;
#pragma unroll
        for (int i = 0; i < 32; ++i) dst[i * 32 + k] = xn[i];   // coalesced across lanes
    }
}

extern "C" void kernel_launch(void* const* d_in, const int* in_sizes, int n_in,
                              void* d_out, int out_size, void* d_ws, size_t ws_size,
                              hipStream_t stream) {
    const float* X     = (const float*)d_in[0];
    // d_in[1] running_mean, d_in[2] running_var: drop out exactly for ETA=1
    const float* meang = (const float*)d_in[3];
    const float* stdg  = (const float*)d_in[4];
    float* out = (float*)d_out;
    float* ws  = (float*)d_ws;
    (void)in_sizes; (void)n_in; (void)out_size;

    // pick passA grid from available workspace
    auto need = [](size_t nblk) -> size_t {
        return (size_t)(32768ull + nblk * 4096ull + nblk * 128ull + 65536ull) * 4ull;
    };
    int NBLK = 512;
    if (ws_size >= need(2048)) NBLK = 2048;
    else if (ws_size >= need(1024)) NBLK = 1024;
    int rounds = NMAT / (NBLK * 8);
    int nhw = NBLK * 8;
    float* gtblk  = ws + OFF_DYN;
    float* sllblk = gtblk + (size_t)NBLK * 4096;
    float* gt2    = sllblk + (size_t)NBLK * 128;

    k_mean1<<<256, 256, 0, stream>>>(X, ws + OFF_PART1);
    k_mean2<<<16, 256, 0, stream>>>(ws + OFF_PART1, ws + OFF_BM);
    k_prep <<<1, 256, 0, stream>>>(ws + OFF_BM, meang, ws + OFF_BMSQ, ws + OFF_BMISQ, ws + OFF_MEANSQ);
    k_passA<<<NBLK, 256, 0, stream>>>(X, ws + OFF_BMISQ, gtblk, sllblk, rounds, nhw);
    k_red  <<<64, 256, 0, stream>>>(gtblk, gt2, NBLK / 16);
    k_stats<<<1, 256, 0, stream>>>(gt2, sllblk, stdg, ws + OFF_BMSQ, ws + OFF_RMISQ, ws + OFF_SVEC, NBLK * 128);
    k_passB<<<2048, 256, 0, stream>>>(X, ws + OFF_RMISQ, ws + OFF_MEANSQ, ws + OFF_SVEC, out);
}

// Round 4
// 2139.633 us; speedup vs baseline: 1.5809x; 1.5809x over previous
//
#include <hip/hip_runtime.h>
#include <math.h>

#define EPSC   1e-6f
#define BNEPS  1e-5f
#define NSWEEP_BULK 6
#define NSWEEP_STAT 8

#define NMAT   16384                // B*C matrices, B=4096, C=4

// static workspace layout (float offsets)
#define OFF_BM      0
#define OFF_BMSQ    4096
#define OFF_BMISQ   8192
#define OFF_MEANSQ  12288
#define OFF_RMISQ   16384
#define OFF_SVEC    20480
#define OFF_PART1   32768           // 256*4096 (k_mean1 only; overlaps gtblk in time)
#define OFF_DYN     32768           // dynamic: gtblk[NBLK*1024] | sllblk[NBLK*32] | gt2[64*1024]

// ---------- device helpers ----------

// One-sided (Hestenes) Jacobi. Lane k of each 32-lane half-wave owns column k.
// XOR-mask pairing: masks 1..31 are perfect matchings covering all pairs/sweep.
template<int SWEEPS>
__device__ __forceinline__ void jacobi32(float a[32], int k) {
    float alpha = 0.f;
#pragma unroll
    for (int i = 0; i < 32; ++i) alpha = fmaf(a[i], a[i], alpha);
#pragma unroll 1
    for (int sweep = 0; sweep < SWEEPS; ++sweep) {
#pragma unroll 1
        for (int m = 1; m < 32; ++m) {
            float q[32];
#pragma unroll
            for (int i = 0; i < 32; ++i) q[i] = __shfl_xor(a[i], m);
            float beta = __shfl_xor(alpha, m);
            float g0 = 0.f, g1 = 0.f, g2 = 0.f, g3 = 0.f;
            float g4 = 0.f, g5 = 0.f, g6 = 0.f, g7 = 0.f;
#pragma unroll
            for (int i = 0; i < 32; i += 8) {
                g0 = fmaf(a[i+0], q[i+0], g0);
                g1 = fmaf(a[i+1], q[i+1], g1);
                g2 = fmaf(a[i+2], q[i+2], g2);
                g3 = fmaf(a[i+3], q[i+3], g3);
                g4 = fmaf(a[i+4], q[i+4], g4);
                g5 = fmaf(a[i+5], q[i+5], g5);
                g6 = fmaf(a[i+6], q[i+6], g6);
                g7 = fmaf(a[i+7], q[i+7], g7);
            }
            float gam = ((g0 + g1) + (g2 + g3)) + ((g4 + g5) + (g6 + g7));
            bool isp = (k < (k ^ m));
            float aa = isp ? alpha : beta;   // ||a_p||^2
            float bb = isp ? beta  : alpha;  // ||a_q||^2
            bool tiny = (fabsf(gam) < 1e-30f);
            float tau = (bb - aa) / (2.f * gam);
            float t = copysignf(1.f, tau) / (fabsf(tau) + sqrtf(fmaf(tau, tau, 1.f)));
            t = tiny ? 0.f : t;
            float c = rsqrtf(fmaf(t, t, 1.f));
            float s = t * c;
            float se = isp ? -s : s;
            float te = isp ? -t : t;
#pragma unroll
            for (int i = 0; i < 32; ++i) a[i] = fmaf(se, q[i], c * a[i]);
            alpha = fmaf(te, gam, alpha);    // alpha' = alpha -/+ t*gamma
        }
    }
}

// y = M v; M 32x32 in LDS, columns of 32 floats; broadcast reads (conflict-free).
__device__ __forceinline__ void matvec32(const float* M, const float v[32], float y[32]) {
#pragma unroll
    for (int i = 0; i < 32; ++i) y[i] = 0.f;
#pragma unroll
    for (int j = 0; j < 32; ++j) {
        const float4* col = (const float4*)(M + j * 32);
        float vj = v[j];
#pragma unroll
        for (int cc = 0; cc < 8; ++cc) {
            float4 r = col[cc];
            y[cc*4+0] = fmaf(vj, r.x, y[cc*4+0]);
            y[cc*4+1] = fmaf(vj, r.y, y[cc*4+1]);
            y[cc*4+2] = fmaf(vj, r.z, y[cc*4+2]);
            y[cc*4+3] = fmaf(vj, r.w, y[cc*4+3]);
        }
    }
}

__device__ __forceinline__ void read_vec(const float* M, int k, float v[32]) {
    const float4* src = (const float4*)(M + k * 32);
#pragma unroll
    for (int cc = 0; cc < 8; ++cc) {
        float4 r = src[cc];
        v[cc*4+0] = r.x; v[cc*4+1] = r.y; v[cc*4+2] = r.z; v[cc*4+3] = r.w;
    }
}

__device__ __forceinline__ void stage_vec(float* M, int k, const float v[32]) {
    float4* dst = (float4*)(M + k * 32);
#pragma unroll
    for (int cc = 0; cc < 8; ++cc)
        dst[cc] = make_float4(v[cc*4+0], v[cc*4+1], v[cc*4+2], v[cc*4+3]);
}

// out[i] (+)= sum_j (coef_j * A[k][j]) * Acol_j[i]   (A column-major in LDS)
template<bool ACC, bool USE_COEF>
__device__ __forceinline__ void recon32(const float* Acols, const float* coef, int k, float out[32]) {
    if (!ACC) {
#pragma unroll
        for (int i = 0; i < 32; ++i) out[i] = 0.f;
    }
    for (int j = 0; j < 32; ++j) {
        float w = Acols[j * 32 + k];          // bank k per lane: conflict-free
        if (USE_COEF) w *= coef[j];
        const float4* col = (const float4*)(Acols + j * 32);
#pragma unroll
        for (int cc = 0; cc < 8; ++cc) {
            float4 r = col[cc];
            out[cc*4+0] = fmaf(w, r.x, out[cc*4+0]);
            out[cc*4+1] = fmaf(w, r.y, out[cc*4+1]);
            out[cc*4+2] = fmaf(w, r.z, out[cc*4+2]);
            out[cc*4+3] = fmaf(w, r.w, out[cc*4+3]);
        }
    }
}

// ---------- kernels ----------

__global__ __launch_bounds__(256) void k_mean1(const float* __restrict__ X, float* __restrict__ part) {
    int bi = blockIdx.x;
    int tid = threadIdx.x;
    const float* xb = X + (size_t)bi * 16 * 4096;
#pragma unroll
    for (int q = 0; q < 16; ++q) {
        int e = q * 256 + tid;
        float acc = 0.f;
        for (int b = 0; b < 16; ++b) acc += xb[(size_t)b * 4096 + e];
        part[(size_t)bi * 4096 + e] = acc;
    }
}

__global__ __launch_bounds__(256) void k_mean2(const float* __restrict__ part, float* __restrict__ bm) {
    int e = blockIdx.x * 256 + threadIdx.x;   // 16 blocks
    float acc = 0.f;
    for (int bi = 0; bi < 256; ++bi) acc += part[(size_t)bi * 4096 + e];
    bm[e] = acc * (1.f / 4096.f);
}

// eig(bm[c]) -> bm_sq, bm_isq ; eig(mean[c]) -> mean_sq.  1 block, 8 half-waves.
__global__ __launch_bounds__(256) void k_prep(const float* __restrict__ wsbm, const float* __restrict__ meang,
                                              float* __restrict__ bmsq, float* __restrict__ bmisq,
                                              float* __restrict__ msq) {
    __shared__ __align__(16) float mat[8][1024];
    __shared__ __align__(16) float aslot[8][1024];
    __shared__ float coefA[8][32];
    __shared__ float coefB[4][32];
    int tid = threadIdx.x;
    for (int i = tid; i < 4096; i += 256) {
        ((float*)mat)[i] = wsbm[i];
        ((float*)mat)[4096 + i] = meang[i];
    }
    __syncthreads();
    int hwl = tid >> 5, k = tid & 31;
    float a[32];
    read_vec(mat[hwl], k, a);
    jacobi32<NSWEEP_STAT>(a, k);
    float al = 0.f;
#pragma unroll
    for (int i = 0; i < 32; ++i) al = fmaf(a[i], a[i], al);
    al = fmaxf(al, 1e-30f);
    float lam = sqrtf(al);
    float inv_al = 1.f / al;
    if (hwl < 4) {
        float wc = fmaxf(lam, EPSC);
        float sqw = sqrtf(wc);
        coefA[hwl][k] = sqw * inv_al;            // sqrtm coef
        coefB[hwl][k] = (1.f / sqw) * inv_al;    // invsqrtm coef
    } else {
        float wc = fmaxf(lam, 0.f);
        coefA[hwl][k] = sqrtf(wc) * inv_al;      // sqrtm(mean) coef
    }
    stage_vec(aslot[hwl], k, a);
    __syncthreads();
    float o[32];
    recon32<false, true>(aslot[hwl], coefA[hwl], k, o);
    if (hwl < 4) {
        float* dst = bmsq + hwl * 1024 + k * 32;
#pragma unroll
        for (int i = 0; i < 32; ++i) dst[i] = o[i];
        recon32<false, true>(aslot[hwl], coefB[hwl], k, o);
        float* dst2 = bmisq + hwl * 1024 + k * 32;
#pragma unroll
        for (int i = 0; i < 32; ++i) dst2[i] = o[i];
    } else {
        float* dst = msq + (hwl - 4) * 1024 + k * 32;
#pragma unroll
        for (int i = 0; i < 32; ++i) dst[i] = o[i];
    }
}

// pass A: one channel per block (c = bi&3); 8 half-waves process 8 b-indices.
// S = bm_isq X bm_isq, eig, gt += logm(S), sll += sum log^2(lam).
// slot[hwl]/coef[hwl] are half-wave-private; bmi read-only => NO inner barriers.
__global__ __launch_bounds__(256) void k_passA(const float* __restrict__ X, const float* __restrict__ bmisq_g,
                                               float* __restrict__ gtblk, float* __restrict__ sllblk,
                                               int rounds, int bstride) {
    __shared__ __align__(16) float slot[8][1024];
    __shared__ __align__(16) float bmi[1024];
    __shared__ float coef[8][32];
    __shared__ float sllred[8][32];
    int tid = threadIdx.x;
    int hwl = tid >> 5, k = tid & 31;
    int bi = blockIdx.x;
    int c = bi & 3;
    int b0 = (bi >> 2) * 8 + hwl;
    for (int i = tid; i < 1024; i += 256) bmi[i] = bmisq_g[c * 1024 + i];
    float gt[32];
#pragma unroll
    for (int i = 0; i < 32; ++i) gt[i] = 0.f;
    float sll = 0.f;
    __syncthreads();
#pragma unroll 1
    for (int r = 0; r < rounds; ++r) {
        int g = (b0 + r * bstride) * 4 + c;
        const float4* xg = (const float4*)(X + (size_t)g * 1024);
        float4* xs = (float4*)slot[hwl];
#pragma unroll
        for (int i = 0; i < 8; ++i) xs[i * 32 + k] = xg[i * 32 + k];
        float a[32];
        {
            float mk[32]; read_vec(bmi, k, mk);        // col k of bm_isq (symmetric)
            float y[32];  matvec32(slot[hwl], mk, y);  // X * mk
            matvec32(bmi, y, a);                       // col k of S
        }
        jacobi32<NSWEEP_BULK>(a, k);
        float al = 0.f;
#pragma unroll
        for (int i = 0; i < 32; ++i) al = fmaf(a[i], a[i], al);
        al = fmaxf(al, 1e-30f);
        float lam = sqrtf(al);
        float l = logf(fmaxf(lam, EPSC));
        sll = fmaf(l, l, sll);
        stage_vec(slot[hwl], k, a);
        coef[hwl][k] = l / al;                     // log(lam)/lam^2
        recon32<true, true>(slot[hwl], coef[hwl], k, gt);   // gt += logm(S) col k
    }
    // cross-half-wave tree reduce (all same channel)
    sllred[hwl][k] = sll;
    if (hwl >= 4) stage_vec(slot[hwl], k, gt);
    __syncthreads();
    if (hwl < 4) {
        const float* p = slot[hwl + 4] + k * 32;
#pragma unroll
        for (int i = 0; i < 32; ++i) gt[i] += p[i];
    }
    if (hwl == 2 || hwl == 3) stage_vec(slot[hwl], k, gt);
    __syncthreads();
    if (hwl < 2) {
        const float* p = slot[hwl + 2] + k * 32;
#pragma unroll
        for (int i = 0; i < 32; ++i) gt[i] += p[i];
    }
    if (hwl == 1) stage_vec(slot[1], k, gt);
    __syncthreads();
    if (hwl == 0) {
        const float* p = slot[1] + k * 32;
        float* dst = gtblk + (size_t)bi * 1024 + k * 32;
#pragma unroll
        for (int i = 0; i < 32; ++i) dst[i] = gt[i] + p[i];
        float stot = 0.f;
#pragma unroll
        for (int h = 0; h < 8; ++h) stot += sllred[h][k];
        sllblk[(size_t)bi * 32 + k] = stot;
    }
}

// reduce NBLK block-partials -> 16 segment partials per channel.
// gtblk[bi][1024] has channel bi&3; T blocks per (segment, channel).
__global__ __launch_bounds__(256) void k_red(const float* __restrict__ gtblk, float* __restrict__ gt2, int T) {
    int bi = blockIdx.x;                // 64
    int c = bi & 3, seg = bi >> 2;
    int tid = threadIdx.x;
#pragma unroll
    for (int q = 0; q < 4; ++q) {
        int e = q * 256 + tid;
        float acc = 0.f;
        for (int t = 0; t < T; ++t) {
            int blk = (seg * T + t) * 4 + c;
            acc += gtblk[(size_t)blk * 1024 + e];
        }
        gt2[((size_t)seg * 4 + c) * 1024 + e] = acc;
    }
}

// finish GT, batch_var, s; eig(GT) -> expm -> rm; eig(rm) -> rm_isq.
__global__ __launch_bounds__(256) void k_stats(const float* __restrict__ gt2, const float* __restrict__ sllblk,
                                               const float* __restrict__ stdg, const float* __restrict__ bmsq_g,
                                               float* __restrict__ rmisq_g, float* __restrict__ svec_g,
                                               int slltot) {
    __shared__ __align__(16) float GTl[4][1024];
    __shared__ __align__(16) float bmsq[4][1024];
    __shared__ __align__(16) float slot[8][1024];
    __shared__ float coef[4][32];
    __shared__ float sred[256];
    int tid = threadIdx.x;
    for (int i = tid; i < 4096; i += 256) {
        int cc = i >> 10, e = i & 1023;
        float acc = 0.f;
        for (int seg = 0; seg < 16; ++seg) acc += gt2[((size_t)seg * 4 + cc) * 1024 + e];
        ((float*)GTl)[i] = acc * (1.f / 4096.f);
        ((float*)bmsq)[i] = bmsq_g[i];
    }
    float sacc = 0.f;
    for (int idx = tid; idx < slltot; idx += 256) sacc += sllblk[idx];  // channel ((tid>>5)&3) fixed
    sred[tid] = sacc;
    __syncthreads();
    if (tid < 4) {
        float tot = 0.f;
        for (int kk = 0; kk < 32; ++kk) tot += sred[tid * 32 + kk] + sred[tid * 32 + 128 + kk];
        float sll_mean = tot * (1.f / 4096.f);
        float ssq = 0.f;
        for (int e = 0; e < 1024; ++e) { float v = GTl[tid][e]; ssq = fmaf(v, v, ssq); }
        float bvar = fmaxf(sll_mean - ssq, 0.f);     // batch_var = E||XT||^2 - ||GT||^2
        float s = stdg[tid] / sqrtf(bvar + BNEPS);
        svec_g[tid] = s;
    }
    __syncthreads();
    int hwl = tid >> 5, k = tid & 31;
    // stage 1: eig(GT) (indefinite -> Rayleigh sign), expm, rm = bm_sq expm(GT) bm_sq
    if (hwl < 4) {
        int c = hwl;
        float a[32]; read_vec(GTl[c], k, a);
        jacobi32<NSWEEP_STAT>(a, k);
        float s2 = 0.f;
#pragma unroll
        for (int i = 0; i < 32; ++i) s2 = fmaf(a[i], a[i], s2);
        s2 = fmaxf(s2, 1e-30f);
        float y[32]; matvec32(GTl[c], a, y);
        float num = 0.f;
#pragma unroll
        for (int i = 0; i < 32; ++i) num = fmaf(a[i], y[i], num);
        float rho = num / s2;                       // signed eigenvalue
        coef[hwl][k] = expf(rho) / s2;
        stage_vec(slot[hwl], k, a);
    }
    __syncthreads();
    if (hwl < 4) {
        float ex[32];
        recon32<false, true>(slot[hwl], coef[hwl], k, ex);   // expm(GT) col k
        stage_vec(slot[hwl + 4], k, ex);
    }
    __syncthreads();
    if (hwl < 4) {
        int c = hwl;
        float v1[32]; read_vec(bmsq[c], k, v1);
        float v2[32]; matvec32(slot[hwl + 4], v1, v2);
        float rmc[32]; matvec32(bmsq[c], v2, rmc);           // rm col k
        stage_vec(slot[hwl], k, rmc);
    }
    __syncthreads();
    // stage 2: eig(rm) -> rm_isq
    if (hwl < 4) {
        float a[32]; read_vec(slot[hwl], k, a);
        jacobi32<NSWEEP_STAT>(a, k);
        float al = 0.f;
#pragma unroll
        for (int i = 0; i < 32; ++i) al = fmaf(a[i], a[i], al);
        al = fmaxf(al, 1e-30f);
        float lam = sqrtf(al);
        float wc = fmaxf(lam, EPSC);
        coef[hwl][k] = (1.f / sqrtf(wc)) / al;
        stage_vec(slot[hwl], k, a);
    }
    __syncthreads();
    if (hwl < 4) {
        float o[32];
        recon32<false, true>(slot[hwl], coef[hwl], k, o);
        float* dst = rmisq_g + hwl * 1024 + k * 32;
#pragma unroll
        for (int i = 0; i < 32; ++i) dst[i] = o[i];
    }
}

// pass B: one channel per block. inner = rm_isq X rm_isq, eig,
// Xn = C C^T with C = mean_sq (A' diag(sqrt(lam^s)/lam)). No inner barriers.
__global__ __launch_bounds__(256) void k_passB(const float* __restrict__ X, const float* __restrict__ rmisq_g,
                                               const float* __restrict__ msq_g, const float* __restrict__ svec_g,
                                               float* __restrict__ out) {
    __shared__ __align__(16) float slot[8][1024];
    __shared__ __align__(16) float rmi[1024];
    __shared__ __align__(16) float msl[1024];
    int tid = threadIdx.x;
    int hwl = tid >> 5, k = tid & 31;
    int bi = blockIdx.x;
    int c = bi & 3;
    int g = ((bi >> 2) * 8 + hwl) * 4 + c;
    for (int i = tid; i < 1024; i += 256) {
        rmi[i] = rmisq_g[c * 1024 + i];
        msl[i] = msq_g[c * 1024 + i];
    }
    float sv = svec_g[c];                           // uniform, L1 hit
    __syncthreads();
    const float4* xg = (const float4*)(X + (size_t)g * 1024);
    float4* xs = (float4*)slot[hwl];
#pragma unroll
    for (int i = 0; i < 8; ++i) xs[i * 32 + k] = xg[i * 32 + k];
    float a[32];
    {
        float t1[32]; read_vec(rmi, k, t1);
        float t2[32]; matvec32(slot[hwl], t1, t2);
        matvec32(rmi, t2, a);                        // inner col k
    }
    jacobi32<NSWEEP_BULK>(a, k);
    float al = 0.f;
#pragma unroll
    for (int i = 0; i < 32; ++i) al = fmaf(a[i], a[i], al);
    al = fmaxf(al, 1e-30f);
    float lam = sqrtf(al);
    float wc = fmaxf(lam, EPSC);
    float pw = expf(sv * logf(wc));                  // lam^s
    float scl = sqrtf(pw / al);
#pragma unroll
    for (int i = 0; i < 32; ++i) a[i] *= scl;
    float cc[32]; matvec32(msl, a, cc);              // C col k = mean_sq * bh
    stage_vec(slot[hwl], k, cc);
    float xn[32];
    recon32<false, false>(slot[hwl], (const float*)nullptr, k, xn);  // Xn = C C^T col k
    float* dst = out + (size_t)g * 1024;
#pragma unroll
    for (int i = 0; i < 32; ++i) dst[i * 32 + k] = xn[i];   // coalesced across lanes
}

extern "C" void kernel_launch(void* const* d_in, const int* in_sizes, int n_in,
                              void* d_out, int out_size, void* d_ws, size_t ws_size,
                              hipStream_t stream) {
    const float* X     = (const float*)d_in[0];
    // d_in[1] running_mean, d_in[2] running_var: drop out exactly for ETA=1
    const float* meang = (const float*)d_in[3];
    const float* stdg  = (const float*)d_in[4];
    float* out = (float*)d_out;
    float* ws  = (float*)d_ws;
    (void)in_sizes; (void)n_in; (void)out_size;

    auto need = [](size_t nblk) -> size_t {
        return (size_t)(32768ull + nblk * 1024ull + nblk * 32ull + 65536ull) * 4ull;
    };
    int NBLK = 512;
    if (ws_size >= need(2048)) NBLK = 2048;
    else if (ws_size >= need(1024)) NBLK = 1024;
    int rounds = 4096 / (NBLK * 2);   // b-indices per half-wave
    int bstride = NBLK * 2;
    float* gtblk  = ws + OFF_DYN;
    float* sllblk = gtblk + (size_t)NBLK * 1024;
    float* gt2    = sllblk + (size_t)NBLK * 32;

    k_mean1<<<256, 256, 0, stream>>>(X, ws + OFF_PART1);
    k_mean2<<<16, 256, 0, stream>>>(ws + OFF_PART1, ws + OFF_BM);
    k_prep <<<1, 256, 0, stream>>>(ws + OFF_BM, meang, ws + OFF_BMSQ, ws + OFF_BMISQ, ws + OFF_MEANSQ);
    k_passA<<<NBLK, 256, 0, stream>>>(X, ws + OFF_BMISQ, gtblk, sllblk, rounds, bstride);
    k_red  <<<64, 256, 0, stream>>>(gtblk, gt2, NBLK / 64);   // (NBLK/4)/16 per segment
    k_stats<<<1, 256, 0, stream>>>(gt2, sllblk, stdg, ws + OFF_BMSQ, ws + OFF_RMISQ, ws + OFF_SVEC, NBLK * 32);
    k_passB<<<2048, 256, 0, stream>>>(X, ws + OFF_RMISQ, ws + OFF_MEANSQ, ws + OFF_SVEC, out);
}

// Round 5
// 1646.528 us; speedup vs baseline: 2.0543x; 1.2995x over previous
//
#include <hip/hip_runtime.h>
#include <math.h>

#define EPSC   1e-6f
#define BNEPS  1e-5f
#define NSWEEP_BULK 5
#define NSWEEP_STAT 8

#define NMAT   16384                // B*C matrices, B=4096, C=4

// static workspace layout (float offsets)
#define OFF_BM      0
#define OFF_BMSQ    4096
#define OFF_BMISQ   8192
#define OFF_MEANSQ  12288
#define OFF_RMISQ   16384
#define OFF_SVEC    20480
#define OFF_PART1   32768           // 256*4096 (k_mean1 only; overlaps gtblk in time)
#define OFF_DYN     32768           // dynamic: gtblk[NBLK*1024] | sllblk[NBLK*32] | gt2[64*1024]

// ---------- device helpers ----------

// One-sided (Hestenes) Jacobi. Lane k of each 32-lane half-wave owns column k.
// XOR-mask pairing: masks 1..31 are perfect matchings covering all pairs/sweep.
template<int SWEEPS>
__device__ __forceinline__ void jacobi32(float a[32], int k) {
    float alpha = 0.f;
#pragma unroll
    for (int i = 0; i < 32; ++i) alpha = fmaf(a[i], a[i], alpha);
#pragma unroll 1
    for (int sweep = 0; sweep < SWEEPS; ++sweep) {
#pragma unroll 1
        for (int m = 1; m < 32; ++m) {
            float q[32];
#pragma unroll
            for (int i = 0; i < 32; ++i) q[i] = __shfl_xor(a[i], m);
            float beta = __shfl_xor(alpha, m);
            float g0 = 0.f, g1 = 0.f, g2 = 0.f, g3 = 0.f;
            float g4 = 0.f, g5 = 0.f, g6 = 0.f, g7 = 0.f;
#pragma unroll
            for (int i = 0; i < 32; i += 8) {
                g0 = fmaf(a[i+0], q[i+0], g0);
                g1 = fmaf(a[i+1], q[i+1], g1);
                g2 = fmaf(a[i+2], q[i+2], g2);
                g3 = fmaf(a[i+3], q[i+3], g3);
                g4 = fmaf(a[i+4], q[i+4], g4);
                g5 = fmaf(a[i+5], q[i+5], g5);
                g6 = fmaf(a[i+6], q[i+6], g6);
                g7 = fmaf(a[i+7], q[i+7], g7);
            }
            float gam = ((g0 + g1) + (g2 + g3)) + ((g4 + g5) + (g6 + g7));
            bool isp = (k < (k ^ m));
            float aa = isp ? alpha : beta;   // ||a_p||^2
            float bb = isp ? beta  : alpha;  // ||a_q||^2
            bool tiny = (fabsf(gam) < 1e-30f);
            float tau = (bb - aa) / (2.f * gam);
            float t = copysignf(1.f, tau) / (fabsf(tau) + sqrtf(fmaf(tau, tau, 1.f)));
            t = tiny ? 0.f : t;
            float c = rsqrtf(fmaf(t, t, 1.f));
            float s = t * c;
            float se = isp ? -s : s;
            float te = isp ? -t : t;
#pragma unroll
            for (int i = 0; i < 32; ++i) a[i] = fmaf(se, q[i], c * a[i]);
            alpha = fmaf(te, gam, alpha);    // alpha' = alpha -/+ t*gamma
        }
    }
}

// y = M v; M 32x32 in LDS, columns of 32 floats; broadcast reads (conflict-free).
__device__ __forceinline__ void matvec32(const float* M, const float v[32], float y[32]) {
#pragma unroll
    for (int i = 0; i < 32; ++i) y[i] = 0.f;
#pragma unroll
    for (int j = 0; j < 32; ++j) {
        const float4* col = (const float4*)(M + j * 32);
        float vj = v[j];
#pragma unroll
        for (int cc = 0; cc < 8; ++cc) {
            float4 r = col[cc];
            y[cc*4+0] = fmaf(vj, r.x, y[cc*4+0]);
            y[cc*4+1] = fmaf(vj, r.y, y[cc*4+1]);
            y[cc*4+2] = fmaf(vj, r.z, y[cc*4+2]);
            y[cc*4+3] = fmaf(vj, r.w, y[cc*4+3]);
        }
    }
}

__device__ __forceinline__ void read_vec(const float* M, int k, float v[32]) {
    const float4* src = (const float4*)(M + k * 32);
#pragma unroll
    for (int cc = 0; cc < 8; ++cc) {
        float4 r = src[cc];
        v[cc*4+0] = r.x; v[cc*4+1] = r.y; v[cc*4+2] = r.z; v[cc*4+3] = r.w;
    }
}

__device__ __forceinline__ void stage_vec(float* M, int k, const float v[32]) {
    float4* dst = (float4*)(M + k * 32);
#pragma unroll
    for (int cc = 0; cc < 8; ++cc)
        dst[cc] = make_float4(v[cc*4+0], v[cc*4+1], v[cc*4+2], v[cc*4+3]);
}

// out[i] (+)= sum_j (coef_j * A[k][j]) * Acol_j[i]   (A column-major in LDS)
template<bool ACC, bool USE_COEF>
__device__ __forceinline__ void recon32(const float* Acols, const float* coef, int k, float out[32]) {
    if (!ACC) {
#pragma unroll
        for (int i = 0; i < 32; ++i) out[i] = 0.f;
    }
    for (int j = 0; j < 32; ++j) {
        float w = Acols[j * 32 + k];          // bank k per lane: conflict-free
        if (USE_COEF) w *= coef[j];
        const float4* col = (const float4*)(Acols + j * 32);
#pragma unroll
        for (int cc = 0; cc < 8; ++cc) {
            float4 r = col[cc];
            out[cc*4+0] = fmaf(w, r.x, out[cc*4+0]);
            out[cc*4+1] = fmaf(w, r.y, out[cc*4+1]);
            out[cc*4+2] = fmaf(w, r.z, out[cc*4+2]);
            out[cc*4+3] = fmaf(w, r.w, out[cc*4+3]);
        }
    }
}

// ---------- kernels ----------

__global__ __launch_bounds__(256) void k_mean1(const float* __restrict__ X, float* __restrict__ part) {
    int bi = blockIdx.x;
    int tid = threadIdx.x;
    const float* xb = X + (size_t)bi * 16 * 4096;
#pragma unroll
    for (int q = 0; q < 16; ++q) {
        int e = q * 256 + tid;
        float acc = 0.f;
        for (int b = 0; b < 16; ++b) acc += xb[(size_t)b * 4096 + e];
        part[(size_t)bi * 4096 + e] = acc;
    }
}

__global__ __launch_bounds__(256) void k_mean2(const float* __restrict__ part, float* __restrict__ bm) {
    int e = blockIdx.x * 256 + threadIdx.x;   // 16 blocks
    float acc = 0.f;
    for (int bi = 0; bi < 256; ++bi) acc += part[(size_t)bi * 4096 + e];
    bm[e] = acc * (1.f / 4096.f);
}

// eig(bm[c]) -> bm_sq, bm_isq ; eig(mean[c]) -> mean_sq.  1 block, 8 half-waves.
__global__ __launch_bounds__(256) void k_prep(const float* __restrict__ wsbm, const float* __restrict__ meang,
                                              float* __restrict__ bmsq, float* __restrict__ bmisq,
                                              float* __restrict__ msq) {
    __shared__ __align__(16) float mat[8][1024];
    __shared__ __align__(16) float aslot[8][1024];
    __shared__ float coefA[8][32];
    __shared__ float coefB[4][32];
    int tid = threadIdx.x;
    for (int i = tid; i < 4096; i += 256) {
        ((float*)mat)[i] = wsbm[i];
        ((float*)mat)[4096 + i] = meang[i];
    }
    __syncthreads();
    int hwl = tid >> 5, k = tid & 31;
    float a[32];
    read_vec(mat[hwl], k, a);
    jacobi32<NSWEEP_STAT>(a, k);
    float al = 0.f;
#pragma unroll
    for (int i = 0; i < 32; ++i) al = fmaf(a[i], a[i], al);
    al = fmaxf(al, 1e-30f);
    float lam = sqrtf(al);
    float inv_al = 1.f / al;
    if (hwl < 4) {
        float wc = fmaxf(lam, EPSC);
        float sqw = sqrtf(wc);
        coefA[hwl][k] = sqw * inv_al;            // sqrtm coef
        coefB[hwl][k] = (1.f / sqw) * inv_al;    // invsqrtm coef
    } else {
        float wc = fmaxf(lam, 0.f);
        coefA[hwl][k] = sqrtf(wc) * inv_al;      // sqrtm(mean) coef
    }
    stage_vec(aslot[hwl], k, a);
    __syncthreads();
    float o[32];
    recon32<false, true>(aslot[hwl], coefA[hwl], k, o);
    if (hwl < 4) {
        float* dst = bmsq + hwl * 1024 + k * 32;
#pragma unroll
        for (int i = 0; i < 32; ++i) dst[i] = o[i];
        recon32<false, true>(aslot[hwl], coefB[hwl], k, o);
        float* dst2 = bmisq + hwl * 1024 + k * 32;
#pragma unroll
        for (int i = 0; i < 32; ++i) dst2[i] = o[i];
    } else {
        float* dst = msq + (hwl - 4) * 1024 + k * 32;
#pragma unroll
        for (int i = 0; i < 32; ++i) dst[i] = o[i];
    }
}

// pass A single-shot (NBLK=2048, one matrix per half-wave): nothing fat lives
// across jacobi -> VGPR <= 128 -> 4 waves/SIMD (see round-4 post-mortem).
__global__ __launch_bounds__(256) void k_passA1(const float* __restrict__ X, const float* __restrict__ bmisq_g,
                                                float* __restrict__ gtblk, float* __restrict__ sllblk) {
    __shared__ __align__(16) float slot[8][1024];
    __shared__ __align__(16) float bmi[1024];
    __shared__ float coef[8][32];
    __shared__ float sllred[8][32];
    int tid = threadIdx.x;
    int hwl = tid >> 5, k = tid & 31;
    int bi = blockIdx.x;
    int c = bi & 3;
    int g = ((bi >> 2) * 8 + hwl) * 4 + c;
    for (int i = tid; i < 1024; i += 256) bmi[i] = bmisq_g[c * 1024 + i];
    __syncthreads();
    const float4* xg = (const float4*)(X + (size_t)g * 1024);
    float4* xs = (float4*)slot[hwl];
#pragma unroll
    for (int i = 0; i < 8; ++i) xs[i * 32 + k] = xg[i * 32 + k];
    float a[32];
    {
        float mk[32]; read_vec(bmi, k, mk);        // col k of bm_isq (symmetric)
        float y[32];  matvec32(slot[hwl], mk, y);  // X * mk
        matvec32(bmi, y, a);                       // col k of S
    }
    jacobi32<NSWEEP_BULK>(a, k);
    float al = 0.f;
#pragma unroll
    for (int i = 0; i < 32; ++i) al = fmaf(a[i], a[i], al);
    al = fmaxf(al, 1e-30f);
    float lam = sqrtf(al);
    float l = logf(fmaxf(lam, EPSC));
    float sll = l * l;
    stage_vec(slot[hwl], k, a);
    coef[hwl][k] = l / al;                         // log(lam)/lam^2
    float gt[32];
    recon32<false, true>(slot[hwl], coef[hwl], k, gt);   // logm(S) col k
    // cross-half-wave tree reduce (all same channel)
    sllred[hwl][k] = sll;
    if (hwl >= 4) stage_vec(slot[hwl], k, gt);
    __syncthreads();
    if (hwl < 4) {
        const float* p = slot[hwl + 4] + k * 32;
#pragma unroll
        for (int i = 0; i < 32; ++i) gt[i] += p[i];
    }
    if (hwl == 2 || hwl == 3) stage_vec(slot[hwl], k, gt);
    __syncthreads();
    if (hwl < 2) {
        const float* p = slot[hwl + 2] + k * 32;
#pragma unroll
        for (int i = 0; i < 32; ++i) gt[i] += p[i];
    }
    if (hwl == 1) stage_vec(slot[1], k, gt);
    __syncthreads();
    if (hwl == 0) {
        const float* p = slot[1] + k * 32;
        float* dst = gtblk + (size_t)bi * 1024 + k * 32;
#pragma unroll
        for (int i = 0; i < 32; ++i) dst[i] = gt[i] + p[i];
        float stot = 0.f;
#pragma unroll
        for (int h = 0; h < 8; ++h) stot += sllred[h][k];
        sllblk[(size_t)bi * 32 + k] = stot;
    }
}

// pass A looped fallback (small workspace): identical math, r4 structure.
__global__ __launch_bounds__(256) void k_passA(const float* __restrict__ X, const float* __restrict__ bmisq_g,
                                               float* __restrict__ gtblk, float* __restrict__ sllblk,
                                               int rounds, int bstride) {
    __shared__ __align__(16) float slot[8][1024];
    __shared__ __align__(16) float bmi[1024];
    __shared__ float coef[8][32];
    __shared__ float sllred[8][32];
    int tid = threadIdx.x;
    int hwl = tid >> 5, k = tid & 31;
    int bi = blockIdx.x;
    int c = bi & 3;
    int b0 = (bi >> 2) * 8 + hwl;
    for (int i = tid; i < 1024; i += 256) bmi[i] = bmisq_g[c * 1024 + i];
    float gt[32];
#pragma unroll
    for (int i = 0; i < 32; ++i) gt[i] = 0.f;
    float sll = 0.f;
    __syncthreads();
#pragma unroll 1
    for (int r = 0; r < rounds; ++r) {
        int g = (b0 + r * bstride) * 4 + c;
        const float4* xg = (const float4*)(X + (size_t)g * 1024);
        float4* xs = (float4*)slot[hwl];
#pragma unroll
        for (int i = 0; i < 8; ++i) xs[i * 32 + k] = xg[i * 32 + k];
        float a[32];
        {
            float mk[32]; read_vec(bmi, k, mk);
            float y[32];  matvec32(slot[hwl], mk, y);
            matvec32(bmi, y, a);
        }
        jacobi32<NSWEEP_BULK>(a, k);
        float al = 0.f;
#pragma unroll
        for (int i = 0; i < 32; ++i) al = fmaf(a[i], a[i], al);
        al = fmaxf(al, 1e-30f);
        float lam = sqrtf(al);
        float l = logf(fmaxf(lam, EPSC));
        sll = fmaf(l, l, sll);
        stage_vec(slot[hwl], k, a);
        coef[hwl][k] = l / al;
        recon32<true, true>(slot[hwl], coef[hwl], k, gt);
    }
    sllred[hwl][k] = sll;
    if (hwl >= 4) stage_vec(slot[hwl], k, gt);
    __syncthreads();
    if (hwl < 4) {
        const float* p = slot[hwl + 4] + k * 32;
#pragma unroll
        for (int i = 0; i < 32; ++i) gt[i] += p[i];
    }
    if (hwl == 2 || hwl == 3) stage_vec(slot[hwl], k, gt);
    __syncthreads();
    if (hwl < 2) {
        const float* p = slot[hwl + 2] + k * 32;
#pragma unroll
        for (int i = 0; i < 32; ++i) gt[i] += p[i];
    }
    if (hwl == 1) stage_vec(slot[1], k, gt);
    __syncthreads();
    if (hwl == 0) {
        const float* p = slot[1] + k * 32;
        float* dst = gtblk + (size_t)bi * 1024 + k * 32;
#pragma unroll
        for (int i = 0; i < 32; ++i) dst[i] = gt[i] + p[i];
        float stot = 0.f;
#pragma unroll
        for (int h = 0; h < 8; ++h) stot += sllred[h][k];
        sllblk[(size_t)bi * 32 + k] = stot;
    }
}

// reduce NBLK block-partials -> 16 segment partials per channel.
__global__ __launch_bounds__(256) void k_red(const float* __restrict__ gtblk, float* __restrict__ gt2, int T) {
    int bi = blockIdx.x;                // 64
    int c = bi & 3, seg = bi >> 2;
    int tid = threadIdx.x;
#pragma unroll
    for (int q = 0; q < 4; ++q) {
        int e = q * 256 + tid;
        float acc = 0.f;
        for (int t = 0; t < T; ++t) {
            int blk = (seg * T + t) * 4 + c;
            acc += gtblk[(size_t)blk * 1024 + e];
        }
        gt2[((size_t)seg * 4 + c) * 1024 + e] = acc;
    }
}

// finish GT, batch_var, s; eig(GT) -> expm -> rm; eig(rm) -> rm_isq.
__global__ __launch_bounds__(256) void k_stats(const float* __restrict__ gt2, const float* __restrict__ sllblk,
                                               const float* __restrict__ stdg, const float* __restrict__ bmsq_g,
                                               float* __restrict__ rmisq_g, float* __restrict__ svec_g,
                                               int slltot) {
    __shared__ __align__(16) float GTl[4][1024];
    __shared__ __align__(16) float bmsq[4][1024];
    __shared__ __align__(16) float slot[8][1024];
    __shared__ float coef[4][32];
    __shared__ float sred[256];
    int tid = threadIdx.x;
    for (int i = tid; i < 4096; i += 256) {
        int cc = i >> 10, e = i & 1023;
        float acc = 0.f;
        for (int seg = 0; seg < 16; ++seg) acc += gt2[((size_t)seg * 4 + cc) * 1024 + e];
        ((float*)GTl)[i] = acc * (1.f / 4096.f);
        ((float*)bmsq)[i] = bmsq_g[i];
    }
    float sacc = 0.f;
    for (int idx = tid; idx < slltot; idx += 256) sacc += sllblk[idx];  // channel ((tid>>5)&3) fixed
    sred[tid] = sacc;
    __syncthreads();
    if (tid < 4) {
        float tot = 0.f;
        for (int kk = 0; kk < 32; ++kk) tot += sred[tid * 32 + kk] + sred[tid * 32 + 128 + kk];
        float sll_mean = tot * (1.f / 4096.f);
        float ssq = 0.f;
        for (int e = 0; e < 1024; ++e) { float v = GTl[tid][e]; ssq = fmaf(v, v, ssq); }
        float bvar = fmaxf(sll_mean - ssq, 0.f);     // batch_var = E||XT||^2 - ||GT||^2
        float s = stdg[tid] / sqrtf(bvar + BNEPS);
        svec_g[tid] = s;
    }
    __syncthreads();
    int hwl = tid >> 5, k = tid & 31;
    // stage 1: eig(GT) (indefinite -> Rayleigh sign), expm, rm = bm_sq expm(GT) bm_sq
    if (hwl < 4) {
        int c = hwl;
        float a[32]; read_vec(GTl[c], k, a);
        jacobi32<NSWEEP_STAT>(a, k);
        float s2 = 0.f;
#pragma unroll
        for (int i = 0; i < 32; ++i) s2 = fmaf(a[i], a[i], s2);
        s2 = fmaxf(s2, 1e-30f);
        float y[32]; matvec32(GTl[c], a, y);
        float num = 0.f;
#pragma unroll
        for (int i = 0; i < 32; ++i) num = fmaf(a[i], y[i], num);
        float rho = num / s2;                       // signed eigenvalue
        coef[hwl][k] = expf(rho) / s2;
        stage_vec(slot[hwl], k, a);
    }
    __syncthreads();
    if (hwl < 4) {
        float ex[32];
        recon32<false, true>(slot[hwl], coef[hwl], k, ex);   // expm(GT) col k
        stage_vec(slot[hwl + 4], k, ex);
    }
    __syncthreads();
    if (hwl < 4) {
        int c = hwl;
        float v1[32]; read_vec(bmsq[c], k, v1);
        float v2[32]; matvec32(slot[hwl + 4], v1, v2);
        float rmc[32]; matvec32(bmsq[c], v2, rmc);           // rm col k
        stage_vec(slot[hwl], k, rmc);
    }
    __syncthreads();
    // stage 2: eig(rm) -> rm_isq
    if (hwl < 4) {
        float a[32]; read_vec(slot[hwl], k, a);
        jacobi32<NSWEEP_STAT>(a, k);
        float al = 0.f;
#pragma unroll
        for (int i = 0; i < 32; ++i) al = fmaf(a[i], a[i], al);
        al = fmaxf(al, 1e-30f);
        float lam = sqrtf(al);
        float wc = fmaxf(lam, EPSC);
        coef[hwl][k] = (1.f / sqrtf(wc)) / al;
        stage_vec(slot[hwl], k, a);
    }
    __syncthreads();
    if (hwl < 4) {
        float o[32];
        recon32<false, true>(slot[hwl], coef[hwl], k, o);
        float* dst = rmisq_g + hwl * 1024 + k * 32;
#pragma unroll
        for (int i = 0; i < 32; ++i) dst[i] = o[i];
    }
}

// pass B: one channel per block. inner = rm_isq X rm_isq, eig,
// Xn = C C^T with C = mean_sq (A' diag(sqrt(lam^s)/lam)). No inner barriers.
__global__ __launch_bounds__(256) void k_passB(const float* __restrict__ X, const float* __restrict__ rmisq_g,
                                               const float* __restrict__ msq_g, const float* __restrict__ svec_g,
                                               float* __restrict__ out) {
    __shared__ __align__(16) float slot[8][1024];
    __shared__ __align__(16) float rmi[1024];
    __shared__ __align__(16) float msl[1024];
    int tid = threadIdx.x;
    int hwl = tid >> 5, k = tid & 31;
    int bi = blockIdx.x;
    int c = bi & 3;
    int g = ((bi >> 2) * 8 + hwl) * 4 + c;
    for (int i = tid; i < 1024; i += 256) {
        rmi[i] = rmisq_g[c * 1024 + i];
        msl[i] = msq_g[c * 1024 + i];
    }
    float sv = svec_g[c];                           // uniform, L1 hit
    __syncthreads();
    const float4* xg = (const float4*)(X + (size_t)g * 1024);
    float4* xs = (float4*)slot[hwl];
#pragma unroll
    for (int i = 0; i < 8; ++i) xs[i * 32 + k] = xg[i * 32 + k];
    float a[32];
    {
        float t1[32]; read_vec(rmi, k, t1);
        float t2[32]; matvec32(slot[hwl], t1, t2);
        matvec32(rmi, t2, a);                        // inner col k
    }
    jacobi32<NSWEEP_BULK>(a, k);
    float al = 0.f;
#pragma unroll
    for (int i = 0; i < 32; ++i) al = fmaf(a[i], a[i], al);
    al = fmaxf(al, 1e-30f);
    float lam = sqrtf(al);
    float wc = fmaxf(lam, EPSC);
    float pw = expf(sv * logf(wc));                  // lam^s
    float scl = sqrtf(pw / al);
#pragma unroll
    for (int i = 0; i < 32; ++i) a[i] *= scl;
    float cc[32]; matvec32(msl, a, cc);              // C col k = mean_sq * bh
    stage_vec(slot[hwl], k, cc);
    float xn[32];
    recon32<false, false>(slot[hwl], (const float*)nullptr, k, xn);  // Xn = C C^T col k
    float* dst = out + (size_t)g * 1024;
#pragma unroll
    for (int i = 0; i < 32; ++i) dst[i * 32 + k] = xn[i];   // coalesced across lanes
}

extern "C" void kernel_launch(void* const* d_in, const int* in_sizes, int n_in,
                              void* d_out, int out_size, void* d_ws, size_t ws_size,
                              hipStream_t stream) {
    const float* X     = (const float*)d_in[0];
    // d_in[1] running_mean, d_in[2] running_var: drop out exactly for ETA=1
    const float* meang = (const float*)d_in[3];
    const float* stdg  = (const float*)d_in[4];
    float* out = (float*)d_out;
    float* ws  = (float*)d_ws;
    (void)in_sizes; (void)n_in; (void)out_size;

    auto need = [](size_t nblk) -> size_t {
        return (size_t)(32768ull + nblk * 1024ull + nblk * 32ull + 65536ull) * 4ull;
    };
    int NBLK = 512;
    if (ws_size >= need(2048)) NBLK = 2048;
    else if (ws_size >= need(1024)) NBLK = 1024;
    int rounds = 4096 / (NBLK * 2);   // b-indices per half-wave
    int bstride = NBLK * 2;
    float* gtblk  = ws + OFF_DYN;
    float* sllblk = gtblk + (size_t)NBLK * 1024;
    float* gt2    = sllblk + (size_t)NBLK * 32;

    k_mean1<<<256, 256, 0, stream>>>(X, ws + OFF_PART1);
    k_mean2<<<16, 256, 0, stream>>>(ws + OFF_PART1, ws + OFF_BM);
    k_prep <<<1, 256, 0, stream>>>(ws + OFF_BM, meang, ws + OFF_BMSQ, ws + OFF_BMISQ, ws + OFF_MEANSQ);
    if (NBLK == 2048) {
        k_passA1<<<2048, 256, 0, stream>>>(X, ws + OFF_BMISQ, gtblk, sllblk);
    } else {
        k_passA<<<NBLK, 256, 0, stream>>>(X, ws + OFF_BMISQ, gtblk, sllblk, rounds, bstride);
    }
    k_red  <<<64, 256, 0, stream>>>(gtblk, gt2, NBLK / 64);
    k_stats<<<1, 256, 0, stream>>>(gt2, sllblk, stdg, ws + OFF_BMSQ, ws + OFF_RMISQ, ws + OFF_SVEC, NBLK * 32);
    k_passB<<<2048, 256, 0, stream>>>(X, ws + OFF_RMISQ, ws + OFF_MEANSQ, ws + OFF_SVEC, out);
}